// Round 8
// baseline (323.081 us; speedup 1.0000x reference)
//
#include <hip/hip_runtime.h>
#include <stdint.h>

typedef short short8 __attribute__((ext_vector_type(8)));
typedef short short4_t __attribute__((ext_vector_type(4)));
typedef float f32x4 __attribute__((ext_vector_type(4)));

__device__ __forceinline__ float bf2f(unsigned short u) {
    union { unsigned int i; float f; } v; v.i = ((unsigned int)u) << 16; return v.f;
}
// round-half-up bf16 (max 0.5 ulp, 2 VALU ops)
__device__ __forceinline__ unsigned short f2bf(float f) {
    union { float f; unsigned int i; } v; v.f = f;
    return (unsigned short)((v.i + 0x8000u) >> 16);
}

// ---------------- kernel B: fused projections (grid 256 x 3) ---------------
// Fully self-contained: converts x AND the weights from f32 on the fly
// (k_pre/k_prew eliminated). y=0,1: h path, 128 channels each (halves x
// re-reads vs 4x64-ch blocks). y=2: f,g path (3-term hi/lo).
// Weights transposed in-block: per-lane-column coalesced j-loop reads from
// W[k][c] + ds_write_b128 of 8 k-consecutive bf16 into wT[c][k] LDS rows.
// Outputs in FRAGMENT-LINEAR layouts:
//   fK/gQ: [b][t=key>>4][chunk=(ch>>3)*16+(key&15)][8]  (tile = 512 shorts)
//   hT:    [b][ch>>4][key>>5][chunk=((key&31)>>3)*16+(ch&15)][8 keys]
__global__ __launch_bounds__(256) void k_proj(
    const float* __restrict__ x,
    const float* __restrict__ Wf,
    const float* __restrict__ Wg,
    const float* __restrict__ Wh,
    const float* __restrict__ bfb,
    const float* __restrict__ bgb,
    const float* __restrict__ bhb,
    unsigned short* __restrict__ fKh,
    unsigned short* __restrict__ fKl,
    unsigned short* __restrict__ gQh,
    unsigned short* __restrict__ gQl,
    unsigned short* __restrict__ hT) {
    __shared__ short sm[26496];         // h: [64][138]x + [128][138]W = 53KB
    int tid = threadIdx.x;
    int wave = tid >> 6, lane = tid & 63, lq = lane & 15, quad = lane >> 4;
    int rt = blockIdx.x;
    const float* xb = x + (size_t)rt * 64 * 256;
    f32x4 zero4 = {0.f, 0.f, 0.f, 0.f};

    if (blockIdx.y < 2) {
        // ---- h path: 128 channels, stride-138 tiles (odd dword stride) ----
        const int XO = 0, WO = 64 * 138;
        int cb = blockIdx.y;
        f32x4 acc[8];
#pragma unroll
        for (int i = 0; i < 8; ++i) acc[i] = zero4;

        for (int ph = 0; ph < 2; ++ph) {
            int k0 = ph * 128;
            __syncthreads();
            // x stage (hi only), 8 f32 per thread per u
#pragma unroll
            for (int u = 0; u < 4; ++u) {
                int q = u * 256 + tid;
                int row = q >> 4, kc = q & 15;
                const float* xs = &xb[row * 256 + k0 + kc * 8];
                f32x4 a0 = *(const f32x4*)xs;
                f32x4 a1 = *(const f32x4*)(xs + 4);
                short8 sh;
#pragma unroll
                for (int j = 0; j < 4; ++j) {
                    sh[j] = (short)f2bf(a0[j]);
                    sh[4 + j] = (short)f2bf(a1[j]);
                }
                *(short8*)&sm[XO + row * 138 + kc * 8] = sh;
            }
            // W stage: transpose Wh[k][c] -> wT[c][k] (hi only)
            {
                int c4 = (tid & 31) * 4;    // 4 consecutive channels
                int seg = tid >> 5;         // k sub-block of 16
#pragma unroll
                for (int jj = 0; jj < 2; ++jj) {
                    f32x4 v[8];
#pragma unroll
                    for (int j = 0; j < 8; ++j)
                        v[j] = *(const f32x4*)&Wh[(size_t)(k0 + seg * 16 + jj * 8 + j) * 256 + cb * 128 + c4];
#pragma unroll
                    for (int i = 0; i < 4; ++i) {
                        short8 w;
#pragma unroll
                        for (int j = 0; j < 8; ++j) w[j] = (short)f2bf(v[j][i]);
                        *(short8*)&sm[WO + (c4 + i) * 138 + seg * 16 + jj * 8] = w;
                    }
                }
            }
            __syncthreads();
#pragma unroll
            for (int ks = 0; ks < 4; ++ks) {
                short8 a = *(const short8*)&sm[XO + (wave * 16 + lq) * 138 + ks * 32 + quad * 8];
#pragma unroll
                for (int ct = 0; ct < 8; ++ct) {
                    short8 bfr = *(const short8*)&sm[WO + (lq + 16 * ct) * 138 + ks * 32 + quad * 8];
                    acc[ct] = __builtin_amdgcn_mfma_f32_16x16x32_bf16(a, bfr, acc[ct], 0, 0, 0);
                }
            }
        }

        int rowl = wave * 16 + quad * 4;
        int grow0 = rt * 64;
        int bidx = grow0 >> 12, n0 = (grow0 & 4095) + rowl;
#pragma unroll
        for (int ct = 0; ct < 8; ++ct) {
            int c = cb * 128 + lq + 16 * ct;
            float bias = bhb[c];
            short4_t pk;
#pragma unroll
            for (int r = 0; r < 4; ++r) pk[r] = (short)f2bf(acc[ct][r] + bias);
            size_t a8 = (((size_t)(bidx * 16 + (c >> 4)) * 128 + (n0 >> 5)) * 64 +
                         ((n0 & 31) >> 3) * 16 + (c & 15)) * 8 + (n0 & 7);
            *(short4_t*)&hT[a8] = pk;
        }
    } else {
        // ---- f,g path (3-term hi/lo), [64][72] tiles ----
        const int XH = 0, XL = 4608, WH = 9216, WL = 13824;
        f32x4 acc[4] = {zero4, zero4, zero4, zero4};

        for (int ph = 0; ph < 4; ++ph) {
            int k0 = ph * 64;
            __syncthreads();
            // x stage hi/lo
#pragma unroll
            for (int u = 0; u < 2; ++u) {
                int q = u * 256 + tid;
                int row = q >> 3, kc = q & 7;
                const float* xs = &xb[row * 256 + k0 + kc * 8];
                f32x4 a0 = *(const f32x4*)xs;
                f32x4 a1 = *(const f32x4*)(xs + 4);
                short8 sh, sl;
#pragma unroll
                for (int j = 0; j < 4; ++j) {
                    unsigned short h0 = f2bf(a0[j]);
                    sh[j] = (short)h0; sl[j] = (short)f2bf(a0[j] - bf2f(h0));
                    unsigned short h1 = f2bf(a1[j]);
                    sh[4 + j] = (short)h1; sl[4 + j] = (short)f2bf(a1[j] - bf2f(h1));
                }
                *(short8*)&sm[XH + row * 72 + kc * 8] = sh;
                *(short8*)&sm[XL + row * 72 + kc * 8] = sl;
            }
            // W stage: Wf (c<32) / Wg transposed, hi+lo
            {
                int c_loc = tid & 63;
                int seg = tid >> 6;         // k sub-block of 16
                const float* wsrc = (c_loc < 32) ? &Wf[c_loc] : &Wg[c_loc - 32];
#pragma unroll
                for (int jj = 0; jj < 2; ++jj) {
                    float v[8];
#pragma unroll
                    for (int j = 0; j < 8; ++j)
                        v[j] = wsrc[(size_t)(k0 + seg * 16 + jj * 8 + j) * 32];
                    short8 shh, sll;
#pragma unroll
                    for (int j = 0; j < 8; ++j) {
                        unsigned short h = f2bf(v[j]);
                        shh[j] = (short)h;
                        sll[j] = (short)f2bf(v[j] - bf2f(h));
                    }
                    *(short8*)&sm[WH + c_loc * 72 + seg * 16 + jj * 8] = shh;
                    *(short8*)&sm[WL + c_loc * 72 + seg * 16 + jj * 8] = sll;
                }
            }
            __syncthreads();
#pragma unroll
            for (int ks = 0; ks < 2; ++ks) {
                short8 ah = *(const short8*)&sm[XH + (wave * 16 + lq) * 72 + ks * 32 + quad * 8];
                short8 al = *(const short8*)&sm[XL + (wave * 16 + lq) * 72 + ks * 32 + quad * 8];
#pragma unroll
                for (int ct = 0; ct < 4; ++ct) {
                    short8 bh = *(const short8*)&sm[WH + (lq + 16 * ct) * 72 + ks * 32 + quad * 8];
                    short8 bl = *(const short8*)&sm[WL + (lq + 16 * ct) * 72 + ks * 32 + quad * 8];
                    acc[ct] = __builtin_amdgcn_mfma_f32_16x16x32_bf16(ah, bh, acc[ct], 0, 0, 0);
                    acc[ct] = __builtin_amdgcn_mfma_f32_16x16x32_bf16(al, bh, acc[ct], 0, 0, 0);
                    acc[ct] = __builtin_amdgcn_mfma_f32_16x16x32_bf16(ah, bl, acc[ct], 0, 0, 0);
                }
            }
        }

        int rowl = wave * 16 + quad * 4;
#pragma unroll
        for (int ct = 0; ct < 4; ++ct) {
            int coll = lq + 16 * ct;
#pragma unroll
            for (int r = 0; r < 4; ++r) {
                int grow = rt * 64 + rowl + r;
                int bidx = grow >> 12, n = grow & 4095;
                float v = acc[ct][r];
                size_t o = (size_t)(bidx * 256 + (n >> 4)) * 512 +
                           (((coll & 31) >> 3) * 16 + (n & 15)) * 8 + (coll & 7);
                if (coll < 32) {
                    v += bfb[coll];
                    unsigned short h = f2bf(v);
                    fKh[o] = h;
                    fKl[o] = f2bf(v - bf2f(h));
                } else {
                    int cg = coll - 32;
                    size_t og = (size_t)(bidx * 256 + (n >> 4)) * 512 +
                                ((cg >> 3) * 16 + (n & 15)) * 8 + (cg & 7);
                    v += bgb[cg];
                    unsigned short h = f2bf(v);
                    gQh[og] = h;
                    gQl[og] = f2bf(v - bf2f(h));
                }
            }
        }
    }
}

// ---------------- kernel C: flash attention (R7 loop + fused combine) ------
// Grid 512 x 512 thr -> (b = bid&3, qt [64-row q tile], ks = key half).
// Main loop IDENTICAL to R7 (60 VGPR, 128-reg class, 16 waves/CU).
// Tail: R5's proven ticket handshake -- both halves write partials (ks=0 ->
// out, ks=1 -> pacc1) + per-row l; threadfence + atomicAdd ticket; the
// SECOND arriver reads partner partials (same XCD: bid and bid+256 share
// bid%8), combines with its in-register acc, normalizes, applies gamma +
// residual, writes final out. k_combine eliminated.
#define PSTR 72
__global__ __launch_bounds__(512, 4) void k_attn(
    const unsigned short* __restrict__ fKh,
    const unsigned short* __restrict__ fKl,
    const unsigned short* __restrict__ gQh,
    const unsigned short* __restrict__ gQl,
    const unsigned short* __restrict__ hT,
    const float* __restrict__ x,
    const float* __restrict__ gam_p,
    float* __restrict__ out,
    float* __restrict__ pacc1,
    float* __restrict__ pl,
    int* __restrict__ flags) {
    __shared__ short Ps[2][64 * PSTR];   // 18.4 KB dbuf P (64x64 pad 72)
    __shared__ short Fb[2][2][2048];     // 16 KB dbuf f hi/lo (64x32 frag-linear)
    __shared__ float Lred[4][16][2];     // 512 B l cross-wave (kh) reduce
    __shared__ int tick_s;
    int tid = threadIdx.x;
    int wave = tid >> 6, lane = tid & 63, lq = lane & 15, quad = lane >> 4;
    int b = blockIdx.x & 3;
    int rest = blockIdx.x >> 2;
    int qt = rest & 63;
    int ks = rest >> 6;                  // 0 or 1 (key half)
    int rs = wave >> 1;                  // row strip 0..3 (16 rows)
    int kh = wave & 1;                   // key-half of phase
    int lchunk = quad * 16 + lq;         // fragment chunk index for this lane

    const unsigned short* fhB = fKh + (size_t)b * 131072;
    const unsigned short* flB = fKl + (size_t)b * 131072;
    const unsigned short* hB  = hT + (size_t)b * 1048576;

    f32x4 zero4 = {0.f, 0.f, 0.f, 0.f};
    f32x4 acc[8];                        // [rb(4)][ct(2)] : 64 rows x 32 ch
#pragma unroll
    for (int i = 0; i < 8; ++i) acc[i] = zero4;
    float l_part[4] = {0.f, 0.f, 0.f, 0.f};

    // g A-frags: row-tile of this wave's strip
    int gtile = b * 256 + qt * 4 + rs;
    short8 ghfrag = *(const short8*)&gQh[(size_t)gtile * 512 + lchunk * 8];
    short8 glfrag = *(const short8*)&gQl[(size_t)gtile * 512 + lchunk * 8];

    // f staging: waves 0-3 stage hi, waves 4-7 stage lo (wave-uniform split)
    int sid = tid & 255;
    int hl = tid >> 8;
    const unsigned short* fB0 = hl ? flB : fhB;
    int ft0 = ks * 128;                  // first 16-key f tile of this half

    // prologue: stage f(kt=0): 4 tiles = 2048 shorts per hi/lo
    *(short8*)&Fb[0][hl][sid * 8] = *(const short8*)&fB0[(size_t)ft0 * 512 + sid * 8];
    __syncthreads();

    for (int kt = 0; kt < 32; ++kt) {
        int p = kt & 1;
        // ---- next-f prefetch (linear) ----
        int nft = ft0 + (kt < 31 ? kt + 1 : kt) * 4;
        short8 fn = *(const short8*)&fB0[(size_t)nft * 512 + sid * 8];

        // ---- hT B-frags: this wave's 2 channel-tiles x 2 key-groups ----
        int k0 = ks * 64 + kt * 2;       // key-group (32 keys) base
        int ct0 = wave * 2;
        short8 hb00 = *(const short8*)&hB[(((size_t)(ct0 + 0) * 128 + k0 + 0) * 64 + lchunk) * 8];
        short8 hb01 = *(const short8*)&hB[(((size_t)(ct0 + 0) * 128 + k0 + 1) * 64 + lchunk) * 8];
        short8 hb10 = *(const short8*)&hB[(((size_t)(ct0 + 1) * 128 + k0 + 0) * 64 + lchunk) * 8];
        short8 hb11 = *(const short8*)&hB[(((size_t)(ct0 + 1) * 128 + k0 + 1) * 64 + lchunk) * 8];

        // ---- S = g.f^T (3-term hi/lo), 2 tiles: kt4 = kh*2 + {0,1} ----
        short8 fh0 = *(const short8*)&Fb[p][0][(kh * 2 + 0) * 512 + lchunk * 8];
        short8 fl0 = *(const short8*)&Fb[p][1][(kh * 2 + 0) * 512 + lchunk * 8];
        short8 fh1 = *(const short8*)&Fb[p][0][(kh * 2 + 1) * 512 + lchunk * 8];
        short8 fl1 = *(const short8*)&Fb[p][1][(kh * 2 + 1) * 512 + lchunk * 8];
        f32x4 S0 = __builtin_amdgcn_mfma_f32_16x16x32_bf16(ghfrag, fh0, zero4, 0, 0, 0);
        f32x4 S1 = __builtin_amdgcn_mfma_f32_16x16x32_bf16(ghfrag, fh1, zero4, 0, 0, 0);
        S0 = __builtin_amdgcn_mfma_f32_16x16x32_bf16(glfrag, fh0, S0, 0, 0, 0);
        S1 = __builtin_amdgcn_mfma_f32_16x16x32_bf16(glfrag, fh1, S1, 0, 0, 0);
        S0 = __builtin_amdgcn_mfma_f32_16x16x32_bf16(ghfrag, fl0, S0, 0, 0, 0);
        S1 = __builtin_amdgcn_mfma_f32_16x16x32_bf16(ghfrag, fl1, S1, 0, 0, 0);

        // ---- P = exp(S), per-lane l, bf16 to LDS ----
#pragma unroll
        for (int r = 0; r < 4; ++r) {
            S0[r] = __expf(S0[r]);
            S1[r] = __expf(S1[r]);
            l_part[r] += S0[r] + S1[r];
        }
#pragma unroll
        for (int r = 0; r < 4; ++r) {
            int row = rs * 16 + quad * 4 + r;
            Ps[p][row * PSTR + (kh * 2 + 0) * 16 + lq] = (short)f2bf(S0[r]);
            Ps[p][row * PSTR + (kh * 2 + 1) * 16 + lq] = (short)f2bf(S1[r]);
        }

        // ---- stage next f ----
        *(short8*)&Fb[1 - p][hl][sid * 8] = fn;

        __syncthreads();   // P[p] + Fb[1-p] visible; single barrier per phase

        // ---- PV: all 64 rows x this wave's 32 channels ----
#pragma unroll
        for (int rb = 0; rb < 4; ++rb) {
            short8 pa0 = *(const short8*)&Ps[p][(rb * 16 + lq) * PSTR + quad * 8];
            short8 pa1 = *(const short8*)&Ps[p][(rb * 16 + lq) * PSTR + 32 + quad * 8];
            acc[rb * 2 + 0] = __builtin_amdgcn_mfma_f32_16x16x32_bf16(pa0, hb00, acc[rb * 2 + 0], 0, 0, 0);
            acc[rb * 2 + 0] = __builtin_amdgcn_mfma_f32_16x16x32_bf16(pa1, hb01, acc[rb * 2 + 0], 0, 0, 0);
            acc[rb * 2 + 1] = __builtin_amdgcn_mfma_f32_16x16x32_bf16(pa0, hb10, acc[rb * 2 + 1], 0, 0, 0);
            acc[rb * 2 + 1] = __builtin_amdgcn_mfma_f32_16x16x32_bf16(pa1, hb11, acc[rb * 2 + 1], 0, 0, 0);
        }
    }

    // ---- epilogue: reduce l over lq lanes, combine kh halves via LDS ----
#pragma unroll
    for (int r = 0; r < 4; ++r) {
        float s = l_part[r];
        s += __shfl_xor(s, 1);
        s += __shfl_xor(s, 2);
        s += __shfl_xor(s, 4);
        s += __shfl_xor(s, 8);
        if (lq == 0) Lred[rs][quad * 4 + r][kh] = s;
    }
    __syncthreads();
    if (kh == 0 && lq == 0) {
#pragma unroll
        for (int r = 0; r < 4; ++r) {
            int rl = quad * 4 + r;
            pl[ks * 16384 + b * 4096 + qt * 64 + rs * 16 + rl] =
                Lred[rs][rl][0] + Lred[rs][rl][1];
        }
    }

    // ---- write partials: this wave's 32 channels x 64 rows ----
    float* mypart = ks ? pacc1 : out;
#pragma unroll
    for (int rb = 0; rb < 4; ++rb)
#pragma unroll
        for (int ct = 0; ct < 2; ++ct) {
            int c = wave * 32 + ct * 16 + lq;
#pragma unroll
            for (int r = 0; r < 4; ++r) {
                int n = qt * 64 + rb * 16 + quad * 4 + r;
                mypart[((size_t)(b * 4096 + n)) * 256 + c] = acc[rb * 2 + ct][r];
            }
        }

    __threadfence();
    __syncthreads();
    if (tid == 0) tick_s = atomicAdd(&flags[blockIdx.x & 255], 1);
    __syncthreads();
    if (tick_s == 0) return;     // partner will combine
    __threadfence();             // acquire partner's partials

    // ---- combine: partner partials + own acc -> normalize, gamma, residual
    const float* opart = ks ? out : pacc1;
    const float* plp = &pl[(size_t)(1 - ks) * 16384 + b * 4096 + qt * 64];
    float gam = gam_p[0];
#pragma unroll
    for (int rb = 0; rb < 4; ++rb)
#pragma unroll
        for (int r = 0; r < 4; ++r) {
            int row_loc = rb * 16 + quad * 4 + r;
            float l = (Lred[rb][quad * 4 + r][0] + Lred[rb][quad * 4 + r][1]) + plp[row_loc];
            float linv = 1.0f / l;
            size_t rowo = ((size_t)(b * 4096 + qt * 64 + row_loc)) * 256;
#pragma unroll
            for (int ct = 0; ct < 2; ++ct) {
                int c = wave * 32 + ct * 16 + lq;
                float o = acc[rb * 2 + ct][r] + opart[rowo + c];
                out[rowo + c] = gam * o * linv + x[rowo + c];
            }
        }
}

extern "C" void kernel_launch(void* const* d_in, const int* in_sizes, int n_in,
                              void* d_out, int out_size, void* d_ws, size_t ws_size,
                              hipStream_t stream) {
    const float* x   = (const float*)d_in[0];
    const float* Wf  = (const float*)d_in[1];
    const float* bfb = (const float*)d_in[2];
    const float* Wg  = (const float*)d_in[3];
    const float* bgb = (const float*)d_in[4];
    const float* Wh  = (const float*)d_in[5];
    const float* bhb = (const float*)d_in[6];
    const float* gam = (const float*)d_in[7];
    float* out = (float*)d_out;

    char* ws = (char*)d_ws;
    const size_t MI = 1u << 20;
    unsigned short* fKh = (unsigned short*)(ws);                  // 1 MiB
    unsigned short* fKl = (unsigned short*)(ws + 1 * MI);         // 1 MiB
    unsigned short* gQh = (unsigned short*)(ws + 2 * MI);         // 1 MiB
    unsigned short* gQl = (unsigned short*)(ws + 3 * MI);         // 1 MiB
    unsigned short* hT  = (unsigned short*)(ws + 4 * MI);         // 8 MiB
    float* pacc1 = (float*)(ws + 12 * MI);                        // 16 MiB
    float* pl    = (float*)(ws + 28 * MI);                        // 128 KiB
    int*   flags = (int*)(ws + 28 * MI + 128 * 1024);             // 1 KiB

    hipMemsetAsync(flags, 0, 256 * sizeof(int), stream);
    k_proj<<<dim3(256, 3), dim3(256), 0, stream>>>(x, Wf, Wg, Wh, bfb, bgb, bhb,
                                                   fKh, fKl, gQh, gQl, hT);
    k_attn<<<dim3(512), dim3(512), 0, stream>>>(fKh, fKl, gQh, gQl, hT,
                                                x, gam, out, pacc1, pl, flags);
}

// Round 9
// 171.019 us; speedup vs baseline: 1.8891x; 1.8891x over previous
//
#include <hip/hip_runtime.h>
#include <stdint.h>

typedef short short8 __attribute__((ext_vector_type(8)));
typedef short short4_t __attribute__((ext_vector_type(4)));
typedef float f32x4 __attribute__((ext_vector_type(4)));

__device__ __forceinline__ float bf2f(unsigned short u) {
    union { unsigned int i; float f; } v; v.i = ((unsigned int)u) << 16; return v.f;
}
// round-half-up bf16 (max 0.5 ulp, 2 VALU ops)
__device__ __forceinline__ unsigned short f2bf(float f) {
    union { float f; unsigned int i; } v; v.f = f;
    return (unsigned short)((v.i + 0x8000u) >> 16);
}

// ---------------- kernel B: fused projections (grid 256 x 3) ---------------
// Fully self-contained: converts x AND the weights from f32 on the fly.
// y=0,1: h path, 128 channels each. y=2: f,g path (3-term hi/lo).
// Outputs in FRAGMENT-LINEAR layouts:
//   fK/gQ: [b][t=key>>4][chunk=(ch>>3)*16+(key&15)][8]  (tile = 512 shorts)
//   hT:    [b][ch>>4][key>>5][chunk=((key&31)>>3)*16+(ch&15)][8 keys]
__global__ __launch_bounds__(256) void k_proj(
    const float* __restrict__ x,
    const float* __restrict__ Wf,
    const float* __restrict__ Wg,
    const float* __restrict__ Wh,
    const float* __restrict__ bfb,
    const float* __restrict__ bgb,
    const float* __restrict__ bhb,
    unsigned short* __restrict__ fKh,
    unsigned short* __restrict__ fKl,
    unsigned short* __restrict__ gQh,
    unsigned short* __restrict__ gQl,
    unsigned short* __restrict__ hT) {
    __shared__ short sm[26496];         // h: [64][138]x + [128][138]W = 53KB
    int tid = threadIdx.x;
    int wave = tid >> 6, lane = tid & 63, lq = lane & 15, quad = lane >> 4;
    int rt = blockIdx.x;
    const float* xb = x + (size_t)rt * 64 * 256;
    f32x4 zero4 = {0.f, 0.f, 0.f, 0.f};

    if (blockIdx.y < 2) {
        // ---- h path: 128 channels, stride-138 tiles ----
        const int XO = 0, WO = 64 * 138;
        int cb = blockIdx.y;
        f32x4 acc[8];
#pragma unroll
        for (int i = 0; i < 8; ++i) acc[i] = zero4;

        for (int ph = 0; ph < 2; ++ph) {
            int k0 = ph * 128;
            __syncthreads();
#pragma unroll
            for (int u = 0; u < 4; ++u) {
                int q = u * 256 + tid;
                int row = q >> 4, kc = q & 15;
                const float* xs = &xb[row * 256 + k0 + kc * 8];
                f32x4 a0 = *(const f32x4*)xs;
                f32x4 a1 = *(const f32x4*)(xs + 4);
                short8 sh;
#pragma unroll
                for (int j = 0; j < 4; ++j) {
                    sh[j] = (short)f2bf(a0[j]);
                    sh[4 + j] = (short)f2bf(a1[j]);
                }
                *(short8*)&sm[XO + row * 138 + kc * 8] = sh;
            }
            // W stage: transpose Wh[k][c] -> wT[c][k] (hi only)
            {
                int c4 = (tid & 31) * 4;    // 4 consecutive channels
                int seg = tid >> 5;         // k sub-block of 16
#pragma unroll
                for (int jj = 0; jj < 2; ++jj) {
                    f32x4 v[8];
#pragma unroll
                    for (int j = 0; j < 8; ++j)
                        v[j] = *(const f32x4*)&Wh[(size_t)(k0 + seg * 16 + jj * 8 + j) * 256 + cb * 128 + c4];
#pragma unroll
                    for (int i = 0; i < 4; ++i) {
                        short8 w;
#pragma unroll
                        for (int j = 0; j < 8; ++j) w[j] = (short)f2bf(v[j][i]);
                        *(short8*)&sm[WO + (c4 + i) * 138 + seg * 16 + jj * 8] = w;
                    }
                }
            }
            __syncthreads();
#pragma unroll
            for (int ks = 0; ks < 4; ++ks) {
                short8 a = *(const short8*)&sm[XO + (wave * 16 + lq) * 138 + ks * 32 + quad * 8];
#pragma unroll
                for (int ct = 0; ct < 8; ++ct) {
                    short8 bfr = *(const short8*)&sm[WO + (lq + 16 * ct) * 138 + ks * 32 + quad * 8];
                    acc[ct] = __builtin_amdgcn_mfma_f32_16x16x32_bf16(a, bfr, acc[ct], 0, 0, 0);
                }
            }
        }

        int rowl = wave * 16 + quad * 4;
        int grow0 = rt * 64;
        int bidx = grow0 >> 12, n0 = (grow0 & 4095) + rowl;
#pragma unroll
        for (int ct = 0; ct < 8; ++ct) {
            int c = cb * 128 + lq + 16 * ct;
            float bias = bhb[c];
            short4_t pk;
#pragma unroll
            for (int r = 0; r < 4; ++r) pk[r] = (short)f2bf(acc[ct][r] + bias);
            size_t a8 = (((size_t)(bidx * 16 + (c >> 4)) * 128 + (n0 >> 5)) * 64 +
                         ((n0 & 31) >> 3) * 16 + (c & 15)) * 8 + (n0 & 7);
            *(short4_t*)&hT[a8] = pk;
        }
    } else {
        // ---- f,g path (3-term hi/lo), [64][72] tiles ----
        const int XH = 0, XL = 4608, WH = 9216, WL = 13824;
        f32x4 acc[4] = {zero4, zero4, zero4, zero4};

        for (int ph = 0; ph < 4; ++ph) {
            int k0 = ph * 64;
            __syncthreads();
#pragma unroll
            for (int u = 0; u < 2; ++u) {
                int q = u * 256 + tid;
                int row = q >> 3, kc = q & 7;
                const float* xs = &xb[row * 256 + k0 + kc * 8];
                f32x4 a0 = *(const f32x4*)xs;
                f32x4 a1 = *(const f32x4*)(xs + 4);
                short8 sh, sl;
#pragma unroll
                for (int j = 0; j < 4; ++j) {
                    unsigned short h0 = f2bf(a0[j]);
                    sh[j] = (short)h0; sl[j] = (short)f2bf(a0[j] - bf2f(h0));
                    unsigned short h1 = f2bf(a1[j]);
                    sh[4 + j] = (short)h1; sl[4 + j] = (short)f2bf(a1[j] - bf2f(h1));
                }
                *(short8*)&sm[XH + row * 72 + kc * 8] = sh;
                *(short8*)&sm[XL + row * 72 + kc * 8] = sl;
            }
            // W stage: Wf (c<32) / Wg transposed, hi+lo
            {
                int c_loc = tid & 63;
                int seg = tid >> 6;         // k sub-block of 16
                const float* wsrc = (c_loc < 32) ? &Wf[c_loc] : &Wg[c_loc - 32];
#pragma unroll
                for (int jj = 0; jj < 2; ++jj) {
                    float v[8];
#pragma unroll
                    for (int j = 0; j < 8; ++j)
                        v[j] = wsrc[(size_t)(k0 + seg * 16 + jj * 8 + j) * 32];
                    short8 shh, sll;
#pragma unroll
                    for (int j = 0; j < 8; ++j) {
                        unsigned short h = f2bf(v[j]);
                        shh[j] = (short)h;
                        sll[j] = (short)f2bf(v[j] - bf2f(h));
                    }
                    *(short8*)&sm[WH + c_loc * 72 + seg * 16 + jj * 8] = shh;
                    *(short8*)&sm[WL + c_loc * 72 + seg * 16 + jj * 8] = sll;
                }
            }
            __syncthreads();
#pragma unroll
            for (int ks = 0; ks < 2; ++ks) {
                short8 ah = *(const short8*)&sm[XH + (wave * 16 + lq) * 72 + ks * 32 + quad * 8];
                short8 al = *(const short8*)&sm[XL + (wave * 16 + lq) * 72 + ks * 32 + quad * 8];
#pragma unroll
                for (int ct = 0; ct < 4; ++ct) {
                    short8 bh = *(const short8*)&sm[WH + (lq + 16 * ct) * 72 + ks * 32 + quad * 8];
                    short8 bl = *(const short8*)&sm[WL + (lq + 16 * ct) * 72 + ks * 32 + quad * 8];
                    acc[ct] = __builtin_amdgcn_mfma_f32_16x16x32_bf16(ah, bh, acc[ct], 0, 0, 0);
                    acc[ct] = __builtin_amdgcn_mfma_f32_16x16x32_bf16(al, bh, acc[ct], 0, 0, 0);
                    acc[ct] = __builtin_amdgcn_mfma_f32_16x16x32_bf16(ah, bl, acc[ct], 0, 0, 0);
                }
            }
        }

        int rowl = wave * 16 + quad * 4;
#pragma unroll
        for (int ct = 0; ct < 4; ++ct) {
            int coll = lq + 16 * ct;
#pragma unroll
            for (int r = 0; r < 4; ++r) {
                int grow = rt * 64 + rowl + r;
                int bidx = grow >> 12, n = grow & 4095;
                float v = acc[ct][r];
                size_t o = (size_t)(bidx * 256 + (n >> 4)) * 512 +
                           (((coll & 31) >> 3) * 16 + (n & 15)) * 8 + (coll & 7);
                if (coll < 32) {
                    v += bfb[coll];
                    unsigned short h = f2bf(v);
                    fKh[o] = h;
                    fKl[o] = f2bf(v - bf2f(h));
                } else {
                    int cg = coll - 32;
                    size_t og = (size_t)(bidx * 256 + (n >> 4)) * 512 +
                                ((cg >> 3) * 16 + (n & 15)) * 8 + (cg & 7);
                    v += bgb[cg];
                    unsigned short h = f2bf(v);
                    gQh[og] = h;
                    gQl[og] = f2bf(v - bf2f(h));
                }
            }
        }
    }
}

// ---------------- kernel C: flash attention (channel-split, self-contained) -
// Grid 512 x 512 thr -> (b = bid&3, qt [64-row q tile], ch = output channel
// HALF). Each block: 64 rows x 128 channels over ALL 4096 keys -> full
// softmax denominator in-block -> normalize + gamma + residual in epilogue.
// NO partials, NO fences, NO combine kernel (channel halves are disjoint).
// S (needs only the 32 f-channels) is computed redundantly by both ch-halves
// (+27% MFMA, cheap). 32 phases of 128 keys, one barrier per phase.
// Wave (rs=w>>1 row-strip, kh=w&1 key-half-of-phase): S = 4 16x16 tiles
// (12 hi/lo MFMA); PV = 64 rows x 16 channels x 128 keys (16 MFMA).
// 28 MFMA/wave/phase -> 448/CU-phase at 2 blocks/CU (R7: 352).
// Live regs ~80 -> 128-class -> 16 waves/CU (the R7-proven requirement).
#define PSTR 136
__global__ __launch_bounds__(512, 4) void k_attn(
    const unsigned short* __restrict__ fKh,
    const unsigned short* __restrict__ fKl,
    const unsigned short* __restrict__ gQh,
    const unsigned short* __restrict__ gQl,
    const unsigned short* __restrict__ hT,
    const float* __restrict__ x,
    const float* __restrict__ gam_p,
    float* __restrict__ out) {
    __shared__ short Ps[2][64 * PSTR];   // 34.8 KB dbuf P (64x128 pad 136)
    __shared__ short Fb[2][2][4096];     // 32 KB dbuf f hi/lo (128key x 32ch)
    __shared__ float Lred[4][16][2];     // 512 B l cross-wave (kh) reduce
    int tid = threadIdx.x;
    int wave = tid >> 6, lane = tid & 63, lq = lane & 15, quad = lane >> 4;
    int b = blockIdx.x & 3;
    int rest = blockIdx.x >> 2;
    int qt = rest & 63;
    int ch = rest >> 6;                  // output channel half 0/1
    int rs = wave >> 1;                  // row strip 0..3 (16 rows)
    int kh = wave & 1;                   // key half of the 128-key phase
    int lchunk = quad * 16 + lq;         // fragment chunk index for this lane

    const unsigned short* fhB = fKh + (size_t)b * 131072;
    const unsigned short* flB = fKl + (size_t)b * 131072;
    const unsigned short* hB  = hT + (size_t)b * 1048576;

    f32x4 zero4 = {0.f, 0.f, 0.f, 0.f};
    f32x4 acc[4];                        // [rb(4)] : 64 rows x 16 ch
#pragma unroll
    for (int i = 0; i < 4; ++i) acc[i] = zero4;
    float l_part[4] = {0.f, 0.f, 0.f, 0.f};

    // g A-frags: row-tile of this wave's strip
    int gtile = b * 256 + qt * 4 + rs;
    short8 ghfrag = *(const short8*)&gQh[(size_t)gtile * 512 + lchunk * 8];
    short8 glfrag = *(const short8*)&gQl[(size_t)gtile * 512 + lchunk * 8];

    // f staging: waves 0-3 stage hi, waves 4-7 stage lo; 2 stores each
    int sid = tid & 255;
    int hl = tid >> 8;
    const unsigned short* fB0 = hl ? flB : fhB;

    // prologue: stage f(0): 4096 shorts per hi/lo buf
    *(short8*)&Fb[0][hl][sid * 8]        = *(const short8*)&fB0[sid * 8];
    *(short8*)&Fb[0][hl][2048 + sid * 8] = *(const short8*)&fB0[2048 + sid * 8];
    __syncthreads();

    // this wave's single hT channel-tile
    const unsigned short* hp = hB + (size_t)(ch * 8 + wave) * 65536;

    for (int t = 0; t < 32; ++t) {
        int p = t & 1;
        // ---- next-f prefetch (regs) ----
        size_t gn = (size_t)(t < 31 ? t + 1 : t) * 4096;
        short8 fn0 = *(const short8*)&fB0[gn + sid * 8];
        short8 fn1 = *(const short8*)&fB0[gn + 2048 + sid * 8];

        // ---- hT B-frags: 4 key-groups (32 keys) of this phase ----
        short8 hb0 = *(const short8*)&hp[((size_t)(t * 4 + 0) * 64 + lchunk) * 8];
        short8 hb1 = *(const short8*)&hp[((size_t)(t * 4 + 1) * 64 + lchunk) * 8];
        short8 hb2 = *(const short8*)&hp[((size_t)(t * 4 + 2) * 64 + lchunk) * 8];
        short8 hb3 = *(const short8*)&hp[((size_t)(t * 4 + 3) * 64 + lchunk) * 8];

        // ---- S = g.f^T (3-term hi/lo), 4 tiles (this wave's 64-key half) --
        f32x4 S[4];
#pragma unroll
        for (int tt = 0; tt < 4; ++tt) {
            short8 fh = *(const short8*)&Fb[p][0][(kh * 4 + tt) * 512 + lchunk * 8];
            short8 fl = *(const short8*)&Fb[p][1][(kh * 4 + tt) * 512 + lchunk * 8];
            S[tt] = __builtin_amdgcn_mfma_f32_16x16x32_bf16(ghfrag, fh, zero4, 0, 0, 0);
            S[tt] = __builtin_amdgcn_mfma_f32_16x16x32_bf16(glfrag, fh, S[tt], 0, 0, 0);
            S[tt] = __builtin_amdgcn_mfma_f32_16x16x32_bf16(ghfrag, fl, S[tt], 0, 0, 0);
        }

        // ---- P = exp(S), per-lane l, bf16 to LDS ----
#pragma unroll
        for (int tt = 0; tt < 4; ++tt)
#pragma unroll
            for (int r = 0; r < 4; ++r) {
                float e = __expf(S[tt][r]);
                S[tt][r] = e;
                l_part[r] += e;
            }
#pragma unroll
        for (int tt = 0; tt < 4; ++tt)
#pragma unroll
            for (int r = 0; r < 4; ++r)
                Ps[p][(rs * 16 + quad * 4 + r) * PSTR + kh * 64 + tt * 16 + lq] =
                    (short)f2bf(S[tt][r]);

        // ---- stage next f ----
        *(short8*)&Fb[1 - p][hl][sid * 8] = fn0;
        *(short8*)&Fb[1 - p][hl][2048 + sid * 8] = fn1;

        __syncthreads();   // P[p] + Fb[1-p] visible; single barrier per phase

        // ---- PV: all 64 rows x this wave's 16 channels x 128 keys ----
#pragma unroll
        for (int rb = 0; rb < 4; ++rb) {
            short8 pa0 = *(const short8*)&Ps[p][(rb * 16 + lq) * PSTR + quad * 8];
            short8 pa1 = *(const short8*)&Ps[p][(rb * 16 + lq) * PSTR + 32 + quad * 8];
            short8 pa2 = *(const short8*)&Ps[p][(rb * 16 + lq) * PSTR + 64 + quad * 8];
            short8 pa3 = *(const short8*)&Ps[p][(rb * 16 + lq) * PSTR + 96 + quad * 8];
            acc[rb] = __builtin_amdgcn_mfma_f32_16x16x32_bf16(pa0, hb0, acc[rb], 0, 0, 0);
            acc[rb] = __builtin_amdgcn_mfma_f32_16x16x32_bf16(pa1, hb1, acc[rb], 0, 0, 0);
            acc[rb] = __builtin_amdgcn_mfma_f32_16x16x32_bf16(pa2, hb2, acc[rb], 0, 0, 0);
            acc[rb] = __builtin_amdgcn_mfma_f32_16x16x32_bf16(pa3, hb3, acc[rb], 0, 0, 0);
        }
    }

    // ---- epilogue: reduce l over lq lanes, combine kh halves via LDS ----
#pragma unroll
    for (int r = 0; r < 4; ++r) {
        float s = l_part[r];
        s += __shfl_xor(s, 1);
        s += __shfl_xor(s, 2);
        s += __shfl_xor(s, 4);
        s += __shfl_xor(s, 8);
        if (lq == 0) Lred[rs][quad * 4 + r][kh] = s;
    }
    __syncthreads();

    // ---- normalize + gamma + residual, write final out ----
    float gam = gam_p[0];
    int c = ch * 128 + wave * 16 + lq;
#pragma unroll
    for (int rb = 0; rb < 4; ++rb)
#pragma unroll
        for (int r = 0; r < 4; ++r) {
            float l = Lred[rb][quad * 4 + r][0] + Lred[rb][quad * 4 + r][1];
            float linv = 1.0f / l;
            int n = qt * 64 + rb * 16 + quad * 4 + r;
            size_t rowo = ((size_t)(b * 4096 + n)) * 256;
            out[rowo + c] = gam * (acc[rb][r] * linv) + x[rowo + c];
        }
}

extern "C" void kernel_launch(void* const* d_in, const int* in_sizes, int n_in,
                              void* d_out, int out_size, void* d_ws, size_t ws_size,
                              hipStream_t stream) {
    const float* x   = (const float*)d_in[0];
    const float* Wf  = (const float*)d_in[1];
    const float* bfb = (const float*)d_in[2];
    const float* Wg  = (const float*)d_in[3];
    const float* bgb = (const float*)d_in[4];
    const float* Wh  = (const float*)d_in[5];
    const float* bhb = (const float*)d_in[6];
    const float* gam = (const float*)d_in[7];
    float* out = (float*)d_out;

    char* ws = (char*)d_ws;
    const size_t MI = 1u << 20;
    unsigned short* fKh = (unsigned short*)(ws);                  // 1 MiB
    unsigned short* fKl = (unsigned short*)(ws + 1 * MI);         // 1 MiB
    unsigned short* gQh = (unsigned short*)(ws + 2 * MI);         // 1 MiB
    unsigned short* gQl = (unsigned short*)(ws + 3 * MI);         // 1 MiB
    unsigned short* hT  = (unsigned short*)(ws + 4 * MI);         // 8 MiB

    k_proj<<<dim3(256, 3), dim3(256), 0, stream>>>(x, Wf, Wg, Wh, bfb, bgb, bhb,
                                                   fKh, fKl, gQh, gQl, hT);
    k_attn<<<dim3(512), dim3(512), 0, stream>>>(fKh, fKl, gQh, gQl, hT,
                                                x, gam, out);
}